// Round 15
// baseline (905.194 us; speedup 1.0000x reference)
//
#include <hip/hip_runtime.h>
#include <hip/hip_bf16.h>

#define NN 4096

typedef unsigned short u16;
using bf16x8 = __attribute__((ext_vector_type(8))) short;
using f32x4  = __attribute__((ext_vector_type(4))) float;

__device__ inline u16 f2bf(float f) {
    union { float f; unsigned u; } c; c.f = f;
    unsigned r = (c.u + 0x7fffu + ((c.u >> 16) & 1u)) >> 16;
    return (u16)r;
}
__device__ inline float bf2f(u16 b) {
    union { unsigned u; float f; } c; c.u = ((unsigned)b) << 16;
    return c.f;
}

__device__ inline void gld16(const void* g, void* l) {
    __builtin_amdgcn_global_load_lds(
        (const __attribute__((address_space(1))) void*)g,
        (__attribute__((address_space(3))) void*)l, 16, 0, 0);
}

// ---------------- f32 -> bf16 convert ----------------
__global__ __launch_bounds__(256) void cvt_bf16(const float* __restrict__ s,
                                                u16* __restrict__ d) {
    size_t i = ((size_t)blockIdx.x * 256 + threadIdx.x) * 8;
    float4 v0 = *(const float4*)(s + i);
    float4 v1 = *(const float4*)(s + i + 4);
    bf16x8 o;
    o[0] = (short)f2bf(v0.x); o[1] = (short)f2bf(v0.y);
    o[2] = (short)f2bf(v0.z); o[3] = (short)f2bf(v0.w);
    o[4] = (short)f2bf(v1.x); o[5] = (short)f2bf(v1.y);
    o[6] = (short)f2bf(v1.z); o[7] = (short)f2bf(v1.w);
    *(bf16x8*)(d + i) = o;
}

// ------- fused weight prep: WrT, WiT, S_A = WrT + WiT in one pass ----------
__global__ __launch_bounds__(256) void wprep(const float* __restrict__ Wr,
                                             const float* __restrict__ Wi,
                                             u16* __restrict__ WrT,
                                             u16* __restrict__ WiT,
                                             u16* __restrict__ SA) {
    __shared__ float tr[32][33], ti[32][33];
    int x  = blockIdx.x * 32 + threadIdx.x;
    int y0 = blockIdx.y * 32;
#pragma unroll
    for (int j = 0; j < 32; j += 8) {
        tr[threadIdx.y + j][threadIdx.x] = Wr[(size_t)(y0 + threadIdx.y + j) * NN + x];
        ti[threadIdx.y + j][threadIdx.x] = Wi[(size_t)(y0 + threadIdx.y + j) * NN + x];
    }
    __syncthreads();
    int x2 = blockIdx.y * 32 + threadIdx.x;
    int y2 = blockIdx.x * 32;
#pragma unroll
    for (int j = 0; j < 32; j += 8) {
        float a = tr[threadIdx.x][threadIdx.y + j];
        float b = ti[threadIdx.x][threadIdx.y + j];
        size_t o = (size_t)(y2 + threadIdx.y + j) * NN + x2;
        WrT[o] = f2bf(a);
        WiT[o] = f2bf(b);
        SA[o]  = f2bf(a + b);
    }
}

// ---------------- bf16 elementwise sum: d = a + b (S_B) ----------------
__global__ __launch_bounds__(256) void presum(const u16* __restrict__ a,
                                              const u16* __restrict__ b,
                                              u16* __restrict__ d) {
    size_t i = ((size_t)blockIdx.x * 256 + threadIdx.x) * 8;
    bf16x8 va = *(const bf16x8*)(a + i);
    bf16x8 vb = *(const bf16x8*)(b + i);
    bf16x8 o;
#pragma unroll
    for (int j = 0; j < 8; j++)
        o[j] = (short)f2bf(bf2f((u16)va[j]) + bf2f((u16)vb[j]));
    *(bf16x8*)(d + i) = o;
}

// ---------------- Karatsuba combine (streaming, R14-verified) ----------------
// outL holds M1, outR holds M3, M2 in ws.  Cr = M1-M2 ; Ci = M3-M1-M2.
__global__ __launch_bounds__(256) void combine(float* __restrict__ out,
                                               const float* __restrict__ M2) {
    size_t i = ((size_t)blockIdx.x * 256 + threadIdx.x) * 4;
    size_t m = i >> 12, n = i & 4095;
    float4 v1 = *(float4*)(out + m * 8192 + n);
    float4 v3 = *(float4*)(out + m * 8192 + 4096 + n);
    float4 v2 = *(const float4*)(M2 + m * 4096 + n);
    float4 cr, ci;
    cr.x = v1.x - v2.x; ci.x = v3.x - v1.x - v2.x;
    cr.y = v1.y - v2.y; ci.y = v3.y - v1.y - v2.y;
    cr.z = v1.z - v2.z; ci.z = v3.z - v1.z - v2.z;
    cr.w = v1.w - v2.w; ci.w = v3.w - v1.w - v2.w;
    *(float4*)(out + m * 8192 + n) = cr;
    *(float4*)(out + m * 8192 + 4096 + n) = ci;
}

// ---- sync primitives (rule #18: sched_barrier after inline waitcnt) ----
#define P_BAR  __builtin_amdgcn_s_barrier()
#define P_SCH  __builtin_amdgcn_sched_barrier(0)
#define P_LGKM do { asm volatile("s_waitcnt lgkmcnt(0)" ::: "memory"); \
                    __builtin_amdgcn_sched_barrier(0); } while (0)
#define LGKM4  do { asm volatile("s_waitcnt lgkmcnt(4)" ::: "memory"); \
                    __builtin_amdgcn_sched_barrier(0); } while (0)
#define VMW(N) do { asm volatile("s_waitcnt vmcnt(" #N ")" ::: "memory"); \
                    __builtin_amdgcn_sched_barrier(0); } while (0)

// ====== 256x256, BK=32, 4-buffer, 3-deep staged, REGISTER-PIPELINED GEMM =====
// C[i][j] = sum_k A[i][k]*B[j][k]. 512 thr = 8 waves (2M x 4N), wave tile
// 128x64. LDS 128 KB (1 block/CU). Stage at step t fills buf (t+3)&3 (3 deep,
// vmcnt(8) steady-state); next tile's a/b frags are read into regs at END of
// step t (after VMW+BAR guarantees buf t+1), so step t+1's first MFMA cluster
// issues with zero operand wait -> covers the c-read drain; 2nd cluster
// covers the read-ahead. Waits: lgkmcnt(4) counted (in-order DS retirement),
// lgkmcnt(0) under CHAIN1 shadow, vmcnt(8->4->0 tail). 1 barrier/step.
// LDS swizzle (R3-proven, 0 conflicts): phys 16B-block p at row r holds
// logical p^((r>>1)&3), via inverse-permuted global source (rule #21).
#define SGA(NB, KN) do { \
    gld16(A + aoff0 + (KN), &sm2[NB][0][tid * 8]); \
    gld16(A + aoff1 + (KN), &sm2[NB][0][4096 + tid * 8]); \
} while (0)
#define SGB(NB, KN) do { \
    gld16(Bp + boff0 + (KN), &sm2[NB][1][tid * 8]); \
    gld16(Bp + boff1 + (KN), &sm2[NB][1][4096 + tid * 8]); \
} while (0)

#define CL16(AF, BF, OFF) do { \
    __builtin_amdgcn_s_setprio(1); \
    _Pragma("unroll") \
    for (int i_ = 0; i_ < 4; i_++) \
        _Pragma("unroll") \
        for (int j_ = 0; j_ < 4; j_++) \
            acc[(OFF) + i_][j_] = __builtin_amdgcn_mfma_f32_16x16x32_bf16(AF[i_], BF[j_], acc[(OFF) + i_][j_], 0, 0, 0); \
    __builtin_amdgcn_s_setprio(0); \
} while (0)

// AC/BC: current frag set (preloaded). AN/BN_: next set (filled at end).
// CBUF: current buf; NBUF=(t+1)&3; SBUF=(t+3)&3; KS=(t+3)*32.
#define STEP(AC, BC, AN, BN_, CBUF, NBUF, SBUF, KS, DOSTG, VWTOK, RDNEXT) do { \
    bf16x8 cfr[4]; \
    _Pragma("unroll") \
    for (int i_ = 0; i_ < 4; i_++) \
        cfr[i_] = *(const bf16x8*)&sm2[CBUF][0][(wr128 + 64 + i_ * 16 + rl) * 32 + kg]; \
    if (DOSTG) { SGA(SBUF, KS); SGB(SBUF, KS); } \
    LGKM4; \
    CL16(AC, BC, 0); \
    P_LGKM; \
    CL16(cfr, BC, 4); \
    VWTOK; P_BAR; P_SCH; \
    if (RDNEXT) { \
        _Pragma("unroll") \
        for (int i_ = 0; i_ < 4; i_++) { \
            AN[i_]  = *(const bf16x8*)&sm2[NBUF][0][(wr128 + i_ * 16 + rl) * 32 + kg]; \
            BN_[i_] = *(const bf16x8*)&sm2[NBUF][1][(wc64  + i_ * 16 + rl) * 32 + kg]; \
        } \
        P_SCH; \
    } \
} while (0)

// OM: 0 = bf16 out (stride NN), 1 = f32 out (stride cs)
template <int OM>
__global__ __launch_bounds__(512, 2) void gemm256k(
    const u16* __restrict__ A, const u16* __restrict__ Bp,
    u16* __restrict__ Cb, float* __restrict__ Cf, int cs) {
    __shared__ u16 sm2[4][2][8192];

    const int brow = blockIdx.y * 256;
    const int bcol = blockIdx.x * 256;

    const int tid  = threadIdx.x;
    const int lane = tid & 63;
    const int wid  = tid >> 6;
    const int wr128 = (wid >> 2) * 128;
    const int wc64  = (wid & 3) * 64;
    const int rl = lane & 15;
    const int kq = lane >> 4;
    const int kg = (kq ^ ((rl >> 1) & 3)) * 8;

    const int r0 = tid >> 2;
    const int lb = (tid & 3) ^ ((r0 >> 1) & 3);
    const size_t aoff0 = (size_t)(brow + r0) * NN + lb * 8;
    const size_t aoff1 = aoff0 + (size_t)128 * NN;
    const size_t boff0 = (size_t)(bcol + r0) * NN + lb * 8;
    const size_t boff1 = boff0 + (size_t)128 * NN;

    f32x4 acc[8][4] = {};
    bf16x8 aX[4], bX[4], aY[4], bY[4];

    // prologue: stage tiles 0,1,2 (3 deep); guarantee tile 0; preload aX,bX
    SGA(0, 0);  SGB(0, 0);
    SGA(1, 32); SGB(1, 32);
    SGA(2, 64); SGB(2, 64);
    VMW(8); P_BAR; P_SCH;
#pragma unroll
    for (int i_ = 0; i_ < 4; i_++) {
        aX[i_] = *(const bf16x8*)&sm2[0][0][(wr128 + i_ * 16 + rl) * 32 + kg];
        bX[i_] = *(const bf16x8*)&sm2[0][1][(wc64  + i_ * 16 + rl) * 32 + kg];
    }
    P_SCH;

    // main: t = 0..123 (4x unroll; buffer indices static)
    for (int tb = 0; tb < 31; ++tb) {
        const size_t k3 = ((size_t)tb * 4 + 3) * 32;
        STEP(aX, bX, aY, bY, 0, 1, 3, k3,       1, VMW(8), 1);
        STEP(aY, bY, aX, bX, 1, 2, 0, k3 + 32,  1, VMW(8), 1);
        STEP(aX, bX, aY, bY, 2, 3, 1, k3 + 64,  1, VMW(8), 1);
        STEP(aY, bY, aX, bX, 3, 0, 2, k3 + 96,  1, VMW(8), 1);
    }
    // tail: t = 124 (stages tile 127), 125, 126, 127
    STEP(aX, bX, aY, bY, 0, 1, 3, (size_t)127 * 32, 1, VMW(8), 1);
    STEP(aY, bY, aX, bX, 1, 2, 0, 0, 0, VMW(4), 1);
    STEP(aX, bX, aY, bY, 2, 3, 0, 0, 0, VMW(0), 1);
    STEP(aY, bY, aX, bX, 3, 0, 0, 0, 0, ((void)0), 0);

    // epilogue: col = bcol + wc*64 + fc*16 + rl, row = brow + wr*128 + fr*16 + kq*4 + e
    const int rg = kq * 4;
#pragma unroll
    for (int fr = 0; fr < 8; fr++)
#pragma unroll
        for (int fc = 0; fc < 4; fc++) {
            const int col = bcol + wc64 + fc * 16 + rl;
#pragma unroll
            for (int e = 0; e < 4; e++) {
                const int row = brow + wr128 + fr * 16 + rg + e;
                if (OM == 0)
                    Cb[(size_t)row * NN + col] = f2bf(acc[fr][fc][e]);
                else
                    Cf[(size_t)row * cs + col] = acc[fr][fc][e];
            }
        }
}

extern "C" void kernel_launch(void* const* d_in, const int* in_sizes, int n_in,
                              void* d_out, int out_size, void* d_ws, size_t ws_size,
                              hipStream_t stream) {
    const float* x  = (const float*)d_in[0];
    const float* Wr = (const float*)d_in[1];
    const float* Wi = (const float*)d_in[2];
    float* out = (float*)d_out;

    const size_t SZ = (size_t)NN * NN;
    u16* ws = (u16*)d_ws;
    u16* s0 = ws;            // xb   -> WrT
    u16* s1 = ws + SZ;       // Wrb  -> WiT
    u16* s2 = ws + 2 * SZ;   // Wib  -> S_A ; later (s2,s3) = M2 f32
    u16* s3 = ws + 3 * SZ;   // Rtr
    u16* s4 = ws + 4 * SZ;   // Rti
    u16* s5 = ws + 5 * SZ;   // S_B
    float* M2 = (float*)s2;  // 64 MB f32 over s2+s3 (both dead by M2 launch)

    // 1) convert inputs to bf16
    cvt_bf16<<<8192, 256, 0, stream>>>(x,  s0);
    cvt_bf16<<<8192, 256, 0, stream>>>(Wr, s1);
    cvt_bf16<<<8192, 256, 0, stream>>>(Wi, s2);

    // 2) pass 1 on gemm256k (bf16 out): Rtr = NT(Wr, x), Rti = NT(Wi, x)
    gemm256k<0><<<dim3(16, 16), 512, 0, stream>>>(s1, s0, s3, nullptr, 0);
    gemm256k<0><<<dim3(16, 16), 512, 0, stream>>>(s2, s0, s4, nullptr, 0);

    // 3) weight prep: WrT -> s0, WiT -> s1, S_A -> s2 ; S_B = Rtr+Rti -> s5
    wprep<<<dim3(128, 128), dim3(32, 8), 0, stream>>>(Wr, Wi, s0, s1, s2);
    presum<<<8192, 256, 0, stream>>>(s3, s4, s5);

    // 4) pass 2 via Karatsuba (order: M3, M1, then M2 into dead s2/s3)
    gemm256k<1><<<dim3(16, 16), 512, 0, stream>>>(s2, s5, nullptr, out + NN, 2 * NN); // M3
    gemm256k<1><<<dim3(16, 16), 512, 0, stream>>>(s0, s3, nullptr, out,      2 * NN); // M1
    gemm256k<1><<<dim3(16, 16), 512, 0, stream>>>(s1, s4, nullptr, M2,       NN);     // M2

    // 5) combine (streaming, full occupancy): Cr = M1-M2, Ci = M3-M1-M2
    combine<<<16384, 256, 0, stream>>>(out, M2);
}

// Round 16
// 735.910 us; speedup vs baseline: 1.2300x; 1.2300x over previous
//
#include <hip/hip_runtime.h>
#include <hip/hip_bf16.h>

#define NN 4096

typedef unsigned short u16;
using bf16x8 = __attribute__((ext_vector_type(8))) short;
using f32x4  = __attribute__((ext_vector_type(4))) float;

__device__ inline u16 f2bf(float f) {
    union { float f; unsigned u; } c; c.f = f;
    unsigned r = (c.u + 0x7fffu + ((c.u >> 16) & 1u)) >> 16;
    return (u16)r;
}
__device__ inline float bf2f(u16 b) {
    union { unsigned u; float f; } c; c.u = ((unsigned)b) << 16;
    return c.f;
}

__device__ inline void gld16(const void* g, void* l) {
    __builtin_amdgcn_global_load_lds(
        (const __attribute__((address_space(1))) void*)g,
        (__attribute__((address_space(3))) void*)l, 16, 0, 0);
}

// ---------------- f32 -> bf16 convert ----------------
__global__ __launch_bounds__(256) void cvt_bf16(const float* __restrict__ s,
                                                u16* __restrict__ d) {
    size_t i = ((size_t)blockIdx.x * 256 + threadIdx.x) * 8;
    float4 v0 = *(const float4*)(s + i);
    float4 v1 = *(const float4*)(s + i + 4);
    bf16x8 o;
    o[0] = (short)f2bf(v0.x); o[1] = (short)f2bf(v0.y);
    o[2] = (short)f2bf(v0.z); o[3] = (short)f2bf(v0.w);
    o[4] = (short)f2bf(v1.x); o[5] = (short)f2bf(v1.y);
    o[6] = (short)f2bf(v1.z); o[7] = (short)f2bf(v1.w);
    *(bf16x8*)(d + i) = o;
}

// ------- fused weight prep: WrT, WiT, S_A = WrT + WiT in one pass ----------
__global__ __launch_bounds__(256) void wprep(const float* __restrict__ Wr,
                                             const float* __restrict__ Wi,
                                             u16* __restrict__ WrT,
                                             u16* __restrict__ WiT,
                                             u16* __restrict__ SA) {
    __shared__ float tr[32][33], ti[32][33];
    int x  = blockIdx.x * 32 + threadIdx.x;
    int y0 = blockIdx.y * 32;
#pragma unroll
    for (int j = 0; j < 32; j += 8) {
        tr[threadIdx.y + j][threadIdx.x] = Wr[(size_t)(y0 + threadIdx.y + j) * NN + x];
        ti[threadIdx.y + j][threadIdx.x] = Wi[(size_t)(y0 + threadIdx.y + j) * NN + x];
    }
    __syncthreads();
    int x2 = blockIdx.y * 32 + threadIdx.x;
    int y2 = blockIdx.x * 32;
#pragma unroll
    for (int j = 0; j < 32; j += 8) {
        float a = tr[threadIdx.x][threadIdx.y + j];
        float b = ti[threadIdx.x][threadIdx.y + j];
        size_t o = (size_t)(y2 + threadIdx.y + j) * NN + x2;
        WrT[o] = f2bf(a);
        WiT[o] = f2bf(b);
        SA[o]  = f2bf(a + b);
    }
}

// ---------------- bf16 elementwise sum: d = a + b (S_B) ----------------
__global__ __launch_bounds__(256) void presum(const u16* __restrict__ a,
                                              const u16* __restrict__ b,
                                              u16* __restrict__ d) {
    size_t i = ((size_t)blockIdx.x * 256 + threadIdx.x) * 8;
    bf16x8 va = *(const bf16x8*)(a + i);
    bf16x8 vb = *(const bf16x8*)(b + i);
    bf16x8 o;
#pragma unroll
    for (int j = 0; j < 8; j++)
        o[j] = (short)f2bf(bf2f((u16)va[j]) + bf2f((u16)vb[j]));
    *(bf16x8*)(d + i) = o;
}

// ---------------- Karatsuba combine (streaming, R14-verified) ----------------
// outL holds M1, outR holds M3, M2 in ws.  Cr = M1-M2 ; Ci = M3-M1-M2.
__global__ __launch_bounds__(256) void combine(float* __restrict__ out,
                                               const float* __restrict__ M2) {
    size_t i = ((size_t)blockIdx.x * 256 + threadIdx.x) * 4;
    size_t m = i >> 12, n = i & 4095;
    float4 v1 = *(float4*)(out + m * 8192 + n);
    float4 v3 = *(float4*)(out + m * 8192 + 4096 + n);
    float4 v2 = *(const float4*)(M2 + m * 4096 + n);
    float4 cr, ci;
    cr.x = v1.x - v2.x; ci.x = v3.x - v1.x - v2.x;
    cr.y = v1.y - v2.y; ci.y = v3.y - v1.y - v2.y;
    cr.z = v1.z - v2.z; ci.z = v3.z - v1.z - v2.z;
    cr.w = v1.w - v2.w; ci.w = v3.w - v1.w - v2.w;
    *(float4*)(out + m * 8192 + n) = cr;
    *(float4*)(out + m * 8192 + 4096 + n) = ci;
}

// ---- sync primitives (rule #18: sched_barrier after inline waitcnt) ----
#define P_BAR  __builtin_amdgcn_s_barrier()
#define P_SCH  __builtin_amdgcn_sched_barrier(0)
#define P_LGKM do { asm volatile("s_waitcnt lgkmcnt(0)" ::: "memory"); \
                    __builtin_amdgcn_sched_barrier(0); } while (0)
#define LGKM4  do { asm volatile("s_waitcnt lgkmcnt(4)" ::: "memory"); \
                    __builtin_amdgcn_sched_barrier(0); } while (0)
#define VMW(N) do { asm volatile("s_waitcnt vmcnt(" #N ")" ::: "memory"); \
                    __builtin_amdgcn_sched_barrier(0); } while (0)

// ========== 256x256-tile, BK=32, 4-LDS-buffer deep-pipelined NT GEMM =========
// (R14-verified structure; R16 delta = all 12 ds_reads issued at step top,
// counted lgkmcnt(4) before CHAIN1 so the c-read drain hides under CHAIN1.)
// C[i][j] = sum_k A[i][k]*B[j][k]. 512 thr = 8 waves (2M x 4N), wave tile
// 128x64. LDS = 4 buf x (A,B) x [256][32] bf16 = 128 KB (1 block/CU).
// Stage at step t targets buf (t+2)&3; vmcnt(4) at phase-top (never 0 until
// tail). LDS swizzle (R3-proven, 0 conflicts): phys 16B-block p at row r
// holds logical p^((r>>1)&3), via inverse-permuted global source (rule #21).
#define SGA(NB, KN) do { \
    gld16(A + aoff0 + (KN), &sm2[NB][0][tid * 8]); \
    gld16(A + aoff1 + (KN), &sm2[NB][0][4096 + tid * 8]); \
} while (0)
#define SGB(NB, KN) do { \
    gld16(Bp + boff0 + (KN), &sm2[NB][1][tid * 8]); \
    gld16(Bp + boff1 + (KN), &sm2[NB][1][4096 + tid * 8]); \
} while (0)

#define K256(CB, NB, KN, DOSTG, V) do { \
    bf16x8 a[4], b[4], c[4]; \
    VMW(V); P_BAR; P_SCH; \
    _Pragma("unroll") \
    for (int i_ = 0; i_ < 4; i_++) \
        a[i_] = *(const bf16x8*)&sm2[CB][0][(wr128 + i_ * 16 + rl) * 32 + kg]; \
    _Pragma("unroll") \
    for (int j_ = 0; j_ < 4; j_++) \
        b[j_] = *(const bf16x8*)&sm2[CB][1][(wc64 + j_ * 16 + rl) * 32 + kg]; \
    _Pragma("unroll") \
    for (int i_ = 0; i_ < 4; i_++) \
        c[i_] = *(const bf16x8*)&sm2[CB][0][(wr128 + 64 + i_ * 16 + rl) * 32 + kg]; \
    if (DOSTG) SGA(NB, KN); \
    LGKM4; \
    __builtin_amdgcn_s_setprio(1); \
    _Pragma("unroll") \
    for (int i_ = 0; i_ < 4; i_++) \
        _Pragma("unroll") \
        for (int j_ = 0; j_ < 4; j_++) \
            acc[i_][j_] = __builtin_amdgcn_mfma_f32_16x16x32_bf16(a[i_], b[j_], acc[i_][j_], 0, 0, 0); \
    __builtin_amdgcn_s_setprio(0); \
    if (DOSTG) SGB(NB, KN); \
    P_LGKM; \
    __builtin_amdgcn_s_setprio(1); \
    _Pragma("unroll") \
    for (int i_ = 0; i_ < 4; i_++) \
        _Pragma("unroll") \
        for (int j_ = 0; j_ < 4; j_++) \
            acc[4 + i_][j_] = __builtin_amdgcn_mfma_f32_16x16x32_bf16(c[i_], b[j_], acc[4 + i_][j_], 0, 0, 0); \
    __builtin_amdgcn_s_setprio(0); \
} while (0)

// OM: 0 = bf16 out (stride NN), 1 = f32 out (stride cs)
template <int OM>
__global__ __launch_bounds__(512, 2) void gemm256k(
    const u16* __restrict__ A, const u16* __restrict__ Bp,
    u16* __restrict__ Cb, float* __restrict__ Cf, int cs) {
    __shared__ u16 sm2[4][2][8192];

    const int brow = blockIdx.y * 256;
    const int bcol = blockIdx.x * 256;

    const int tid  = threadIdx.x;
    const int lane = tid & 63;
    const int wid  = tid >> 6;
    const int wr128 = (wid >> 2) * 128;
    const int wc64  = (wid & 3) * 64;
    const int rl = lane & 15;
    const int kq = lane >> 4;
    const int kg = (kq ^ ((rl >> 1) & 3)) * 8;

    const int r0 = tid >> 2;
    const int lb = (tid & 3) ^ ((r0 >> 1) & 3);
    const size_t aoff0 = (size_t)(brow + r0) * NN + lb * 8;
    const size_t aoff1 = aoff0 + (size_t)128 * NN;
    const size_t boff0 = (size_t)(bcol + r0) * NN + lb * 8;
    const size_t boff1 = boff0 + (size_t)128 * NN;

    f32x4 acc[8][4] = {};

    SGA(0, 0); SGB(0, 0); SGA(1, 32); SGB(1, 32);

    for (int tb = 0; tb < 31; ++tb) {
        const size_t k0 = (size_t)tb * 128;
        K256(0, 2, k0 + 64,  1, 4);
        K256(1, 3, k0 + 96,  1, 4);
        K256(2, 0, k0 + 128, 1, 4);
        K256(3, 1, k0 + 160, 1, 4);
    }
    K256(0, 2, 4032, 1, 4);
    K256(1, 3, 4064, 1, 4);
    K256(2, 0, 0,    0, 4);
    K256(3, 0, 0,    0, 0);

    const int rg = kq * 4;
#pragma unroll
    for (int fr = 0; fr < 8; fr++)
#pragma unroll
        for (int fc = 0; fc < 4; fc++) {
            const int col = bcol + wc64 + fc * 16 + rl;
#pragma unroll
            for (int e = 0; e < 4; e++) {
                const int row = brow + wr128 + fr * 16 + rg + e;
                if (OM == 0)
                    Cb[(size_t)row * NN + col] = f2bf(acc[fr][fc][e]);
                else
                    Cf[(size_t)row * cs + col] = acc[fr][fc][e];
            }
        }
}

extern "C" void kernel_launch(void* const* d_in, const int* in_sizes, int n_in,
                              void* d_out, int out_size, void* d_ws, size_t ws_size,
                              hipStream_t stream) {
    const float* x  = (const float*)d_in[0];
    const float* Wr = (const float*)d_in[1];
    const float* Wi = (const float*)d_in[2];
    float* out = (float*)d_out;

    const size_t SZ = (size_t)NN * NN;
    u16* ws = (u16*)d_ws;
    u16* s0 = ws;            // xb   -> WrT
    u16* s1 = ws + SZ;       // Wrb  -> WiT
    u16* s2 = ws + 2 * SZ;   // Wib  -> S_A ; later (s2,s3) = M2 f32
    u16* s3 = ws + 3 * SZ;   // Rtr
    u16* s4 = ws + 4 * SZ;   // Rti
    u16* s5 = ws + 5 * SZ;   // S_B
    float* M2 = (float*)s2;  // 64 MB f32 over s2+s3 (both dead by M2 launch)

    // 1) convert inputs to bf16
    cvt_bf16<<<8192, 256, 0, stream>>>(x,  s0);
    cvt_bf16<<<8192, 256, 0, stream>>>(Wr, s1);
    cvt_bf16<<<8192, 256, 0, stream>>>(Wi, s2);

    // 2) pass 1 on gemm256k (bf16 out): Rtr = NT(Wr, x), Rti = NT(Wi, x)
    gemm256k<0><<<dim3(16, 16), 512, 0, stream>>>(s1, s0, s3, nullptr, 0);
    gemm256k<0><<<dim3(16, 16), 512, 0, stream>>>(s2, s0, s4, nullptr, 0);

    // 3) weight prep: WrT -> s0, WiT -> s1, S_A -> s2 ; S_B = Rtr+Rti -> s5
    wprep<<<dim3(128, 128), dim3(32, 8), 0, stream>>>(Wr, Wi, s0, s1, s2);
    presum<<<8192, 256, 0, stream>>>(s3, s4, s5);

    // 4) pass 2 via Karatsuba (order: M3, M1, then M2 into dead s2/s3)
    gemm256k<1><<<dim3(16, 16), 512, 0, stream>>>(s2, s5, nullptr, out + NN, 2 * NN); // M3
    gemm256k<1><<<dim3(16, 16), 512, 0, stream>>>(s0, s3, nullptr, out,      2 * NN); // M1
    gemm256k<1><<<dim3(16, 16), 512, 0, stream>>>(s1, s4, nullptr, M2,       NN);     // M2

    // 5) combine (streaming, full occupancy): Cr = M1-M2, Ci = M3-M1-M2
    combine<<<16384, 256, 0, stream>>>(out, M2);
}